// Round 6
// baseline (14535.208 us; speedup 1.0000x reference)
//
#include <hip/hip_runtime.h>
#include <stdint.h>
#include <stddef.h>

constexpr int T_STEPS  = 256;
constexpr int B_ROWS   = 4096;
constexpr int D_DIM    = 64;
constexpr int W_DIM    = 256;
constexpr int ROWS_PB  = 8;     // valid rows per block (MFMA M=16, rows 8..15 are padding)
constexpr int NTHREADS = 256;   // 4 waves x 64 output features each; 2 blocks/CU

constexpr int HS_LD = 132;   // hidden-act LDS row stride (dwords): mod 32 = 4 -> bank stagger
constexpr int YB_LD = 36;    // y-act LDS row stride (dwords)

constexpr float LOG2E = 1.44269504088896f;
constexpr float LN2   = 0.693147180559945f;

typedef __attribute__((ext_vector_type(8))) __bf16 bf16x8;
typedef __attribute__((ext_vector_type(8))) short  short8;
typedef __attribute__((ext_vector_type(4))) float  f32x4;

__device__ __forceinline__ unsigned f2bf_bits(float f) {
    union { float f; unsigned u; } v; v.f = f;
    return (v.u + 0x7FFFu + ((v.u >> 16) & 1u)) >> 16;   // RTNE
}

__device__ __forceinline__ uint32_t cvt_pk_bf16(float lo, float hi) {
    uint32_t r;
    asm("v_cvt_pk_bf16_f32 %0, %1, %2" : "=v"(r) : "v"(lo), "v"(hi));
    return r;
}

// Overflow-safe softplus in log2 domain: g(u) = max(u,0) + log2(1 + 2^-|u|).
__device__ __forceinline__ float act_g(float u) {
    float e = __builtin_amdgcn_exp2f(-fabsf(u));
    return fmaxf(u, 0.0f) + __builtin_amdgcn_logf(1.0f + e);
}

// B-fragment, interleaved-pair permutation: elem j <-> k = kcb + lg*4 + (j>>1) + 16*(j&1)
__device__ __forceinline__ bf16x8 load_wfrag(const float* __restrict__ wg, int ldk,
                                             int f, int kcb, int lg, float scale) {
    const float4 a = *reinterpret_cast<const float4*>(wg + (size_t)f * ldk + kcb + lg * 4);
    const float4 b = *reinterpret_cast<const float4*>(wg + (size_t)f * ldk + kcb + 16 + lg * 4);
    short8 s;
    s[0] = (short)f2bf_bits(a.x * scale); s[1] = (short)f2bf_bits(b.x * scale);
    s[2] = (short)f2bf_bits(a.y * scale); s[3] = (short)f2bf_bits(b.y * scale);
    s[4] = (short)f2bf_bits(a.z * scale); s[5] = (short)f2bf_bits(b.z * scale);
    s[6] = (short)f2bf_bits(a.w * scale); s[7] = (short)f2bf_bits(b.w * scale);
    return __builtin_bit_cast(bf16x8, s);
}

// One hidden layer, 4 output tiles (64 features) per wave.
template<int NKC>
__device__ __forceinline__ void mlp_layer4(const uint32_t* __restrict__ src,
                                           uint32_t* __restrict__ dst,
                                           const bf16x8* __restrict__ wf0,
                                           const bf16x8* __restrict__ wf1,
                                           const bf16x8* __restrict__ wf2,
                                           const bf16x8* __restrict__ wf3,
                                           float bv0, float bv1, float bv2, float bv3)
{
    f32x4 a0 = {bv0, bv0, bv0, bv0};
    f32x4 a1 = {bv1, bv1, bv1, bv1};
    f32x4 a2 = {bv2, bv2, bv2, bv2};
    f32x4 a3 = {bv3, bv3, bv3, bv3};
#pragma unroll
    for (int kc = 0; kc < NKC; ++kc) {
        const bf16x8 a = *reinterpret_cast<const bf16x8*>(src + kc * 16);
        a0 = __builtin_amdgcn_mfma_f32_16x16x32_bf16(a, wf0[kc], a0, 0, 0, 0);
        a1 = __builtin_amdgcn_mfma_f32_16x16x32_bf16(a, wf1[kc], a1, 0, 0, 0);
        a2 = __builtin_amdgcn_mfma_f32_16x16x32_bf16(a, wf2[kc], a2, 0, 0, 0);
        a3 = __builtin_amdgcn_mfma_f32_16x16x32_bf16(a, wf3[kc], a3, 0, 0, 0);
    }
#pragma unroll
    for (int j = 0; j < 4; ++j) {
        dst[j * HS_LD]      = cvt_pk_bf16(act_g(a0[j]), act_g(a1[j]));
        dst[j * HS_LD + 16] = cvt_pk_bf16(act_g(a2[j]), act_g(a3[j]));
    }
}

__global__ __launch_bounds__(NTHREADS, 2) void node_rk3_kernel(
    const float* __restrict__ ts,
    const float* __restrict__ y0,
    const float* __restrict__ w0, const float* __restrict__ b0,
    const float* __restrict__ w1, const float* __restrict__ b1,
    const float* __restrict__ w2, const float* __restrict__ b2,
    const float* __restrict__ w3, const float* __restrict__ b3,
    float* __restrict__ out)
{
    __shared__ __align__(16) uint32_t hs0[16][HS_LD];
    __shared__ __align__(16) uint32_t hs1[16][HS_LD];
    __shared__ __align__(16) uint32_t ybf[16][YB_LD];

    const int tid  = threadIdx.x;
    const int lane = tid & 63;
    const int wid  = tid >> 6;        // 0..3
    const int lr   = lane & 15;
    const int lg   = lane >> 4;
    const int row0 = blockIdx.x * ROWS_PB;

    // ---- persistent register-resident weight fragments (pre-scaled) ----
    bf16x8 w0f[4][2], w1f[4][8], w2f[4][8];
#pragma unroll
    for (int nt = 0; nt < 4; ++nt) {
        const int f = wid * 64 + nt * 16 + lr;
#pragma unroll
        for (int kc = 0; kc < 2; ++kc) w0f[nt][kc] = load_wfrag(w0, D_DIM, f, kc * 32, lg, LOG2E);
#pragma unroll
        for (int kc = 0; kc < 8; ++kc) w1f[nt][kc] = load_wfrag(w1, W_DIM, f, kc * 32, lg, 1.0f);
#pragma unroll
        for (int kc = 0; kc < 8; ++kc) w2f[nt][kc] = load_wfrag(w2, W_DIM, f, kc * 32, lg, 1.0f);
    }

    // L3 on waves 0..1 only: wave w owns output features [w*32, w*32+32)
    bf16x8 w3f0[8], w3f1[8];
    float bv3a = 0.f, bv3b = 0.f;
    if (wid < 2) {
#pragma unroll
        for (int kc = 0; kc < 8; ++kc) {
            w3f0[kc] = load_wfrag(w3, W_DIM, wid * 32 + lr,      kc * 32, lg, LN2);
            w3f1[kc] = load_wfrag(w3, W_DIM, wid * 32 + 16 + lr, kc * 32, lg, LN2);
        }
        bv3a = b3[wid * 32 + lr];
        bv3b = b3[wid * 32 + 16 + lr];
    }

    float bA0[4], bA1[4], bA2[4];
#pragma unroll
    for (int nt = 0; nt < 4; ++nt) {
        bA0[nt] = LOG2E * b0[wid * 64 + nt * 16 + lr];
        bA1[nt] = LOG2E * b1[wid * 64 + nt * 16 + lr];
        bA2[nt] = LOG2E * b2[wid * 64 + nt * 16 + lr];
    }

    const float dt = ts[1] - ts[0];

    // ---- per-thread LDS base pointers (all later accesses use imm offsets) ----
    const uint32_t* pA_y  = &ybf[lr][lg * 4];
    const uint32_t* pA_h0 = &hs0[lr][lg * 4];
    const uint32_t* pA_h1 = &hs1[lr][lg * 4];
    uint32_t* pW_h0 = &hs0[lg * 4][wid * 32 + lr];
    uint32_t* pW_h1 = &hs1[lg * 4][wid * 32 + lr];
    uint32_t* pYW   = &ybf[lg * 4][wid * 16 + lr];   // full-dword state write (waves 0..1)

    // ---- per-lane state (waves 0..1, lanes lg<2): y[r=lg*4+j][d=wid*32(+16)+lr] ----
    const bool srow_ok = (wid < 2) && (lg < 2);
    float yra[4], yrb[4], k1a[4], k1b[4], k2a[4], k2b[4], vsta[4], vstb[4];
#pragma unroll
    for (int j = 0; j < 4; ++j) {
        const int r = lg * 4 + j;
        yra[j] = srow_ok ? y0[(size_t)(row0 + r) * D_DIM + wid * 32 + lr]      : 0.f;
        yrb[j] = srow_ok ? y0[(size_t)(row0 + r) * D_DIM + wid * 32 + 16 + lr] : 0.f;
        k1a[j] = 0.f; k1b[j] = 0.f; k2a[j] = 0.f; k2b[j] = 0.f;
        vsta[j] = 0.f; vstb[j] = 0.f;
    }

    // ---- initial packed ybf (rows 0..7 real, rows 8..15 zero padding) ----
    for (int i = tid; i < 16 * 32; i += NTHREADS) {
        const int r = i >> 5, c32 = i & 31, kbi = c32 >> 4, u = c32 & 15;
        uint32_t val = 0;
        if (r < ROWS_PB) {
            const float* yr = y0 + (size_t)(row0 + r) * D_DIM;
            val = cvt_pk_bf16(yr[kbi * 32 + u], yr[kbi * 32 + 16 + u]);
        }
        ybf[r][kbi * 16 + u] = val;
    }
    __syncthreads();

    for (int t = 0; t < T_STEPS; ++t) {
        // deferred global store of step t-1 (overlaps with L0 compute of step t)
        if (t > 0 && srow_ok) {
#pragma unroll
            for (int j = 0; j < 4; ++j) {
                const size_t base = ((size_t)(t - 1) * B_ROWS + row0 + lg * 4 + j) * D_DIM
                                    + wid * 32 + lr;
                out[base]      = vsta[j];
                out[base + 16] = vstb[j];
            }
        }
#pragma unroll
        for (int c = 0; c < 3; ++c) {
            mlp_layer4<2>(pA_y,  pW_h0, w0f[0], w0f[1], w0f[2], w0f[3],
                          bA0[0], bA0[1], bA0[2], bA0[3]);
            __syncthreads();
            mlp_layer4<8>(pA_h0, pW_h1, w1f[0], w1f[1], w1f[2], w1f[3],
                          bA1[0], bA1[1], bA1[2], bA1[3]);
            __syncthreads();
            mlp_layer4<8>(pA_h1, pW_h0, w2f[0], w2f[1], w2f[2], w2f[3],
                          bA2[0], bA2[1], bA2[2], bA2[3]);
            __syncthreads();
            // ---------- layer 3 + in-register RK update (waves 0..1) ----------
            if (wid < 2) {
                f32x4 acc0 = {bv3a, bv3a, bv3a, bv3a};
                f32x4 acc1 = {bv3b, bv3b, bv3b, bv3b};
#pragma unroll
                for (int kc = 0; kc < 8; ++kc) {
                    const bf16x8 a = *reinterpret_cast<const bf16x8*>(pA_h0 + kc * 16);
                    acc0 = __builtin_amdgcn_mfma_f32_16x16x32_bf16(a, w3f0[kc], acc0, 0, 0, 0);
                    acc1 = __builtin_amdgcn_mfma_f32_16x16x32_bf16(a, w3f1[kc], acc1, 0, 0, 0);
                }
#pragma unroll
                for (int j = 0; j < 4; ++j) {
                    float v0, v1;
                    if (c == 0) {
                        k1a[j] = acc0[j]; v0 = fmaf(0.5f, acc0[j], yra[j]);
                        k1b[j] = acc1[j]; v1 = fmaf(0.5f, acc1[j], yrb[j]);
                    } else if (c == 1) {
                        k2a[j] = acc0[j]; v0 = fmaf(0.75f, acc0[j], yra[j]);
                        k2b[j] = acc1[j]; v1 = fmaf(0.75f, acc1[j], yrb[j]);
                    } else {
                        v0 = yra[j] + dt * ((2.0f / 9.0f) * k1a[j]
                                          + (1.0f / 3.0f) * k2a[j]
                                          + (4.0f / 9.0f) * acc0[j]);
                        v1 = yrb[j] + dt * ((2.0f / 9.0f) * k1b[j]
                                          + (1.0f / 3.0f) * k2b[j]
                                          + (4.0f / 9.0f) * acc1[j]);
                        yra[j] = v0; vsta[j] = v0;
                        yrb[j] = v1; vstb[j] = v1;
                    }
                    pYW[j * YB_LD] = cvt_pk_bf16(v0, v1);
                }
            }
            __syncthreads();
        }
    }
    // final step's store
    if (srow_ok) {
#pragma unroll
        for (int j = 0; j < 4; ++j) {
            const size_t base = ((size_t)(T_STEPS - 1) * B_ROWS + row0 + lg * 4 + j) * D_DIM
                                + wid * 32 + lr;
            out[base]      = vsta[j];
            out[base + 16] = vstb[j];
        }
    }
}

extern "C" void kernel_launch(void* const* d_in, const int* in_sizes, int n_in,
                              void* d_out, int out_size, void* d_ws, size_t ws_size,
                              hipStream_t stream) {
    const float* ts = (const float*)d_in[0];
    const float* y0 = (const float*)d_in[1];
    const float* w0 = (const float*)d_in[2];
    const float* b0 = (const float*)d_in[3];
    const float* w1 = (const float*)d_in[4];
    const float* b1 = (const float*)d_in[5];
    const float* w2 = (const float*)d_in[6];
    const float* b2 = (const float*)d_in[7];
    const float* w3 = (const float*)d_in[8];
    const float* b3 = (const float*)d_in[9];
    float* out = (float*)d_out;

    hipLaunchKernelGGL(node_rk3_kernel,
                       dim3(B_ROWS / ROWS_PB), dim3(NTHREADS), 0, stream,
                       ts, y0, w0, b0, w1, b1, w2, b2, w3, b3, out);
}

// Round 7
// 1347.896 us; speedup vs baseline: 10.7836x; 10.7836x over previous
//
#include <hip/hip_runtime.h>
#include <stdint.h>
#include <stddef.h>

constexpr int T_STEPS  = 256;
constexpr int B_ROWS   = 4096;
constexpr int D_DIM    = 64;
constexpr int W_DIM    = 256;
constexpr int ROWS_PB  = 16;
constexpr int NTHREADS = 512;

constexpr int HS_LD = 132;   // hidden-act LDS row stride (dwords): mod 32 = 4 -> bank stagger
constexpr int YB_LD = 36;    // y-act LDS row stride (dwords)

constexpr float LOG2E = 1.44269504088896f;
constexpr float LN2   = 0.693147180559945f;

typedef __attribute__((ext_vector_type(8))) __bf16 bf16x8;
typedef __attribute__((ext_vector_type(8))) short  short8;
typedef __attribute__((ext_vector_type(4))) float  f32x4;

__device__ __forceinline__ unsigned f2bf_bits(float f) {
    union { float f; unsigned u; } v; v.f = f;
    return (v.u + 0x7FFFu + ((v.u >> 16) & 1u)) >> 16;   // RTNE
}

__device__ __forceinline__ uint32_t cvt_pk_bf16(float lo, float hi) {
    uint32_t r;
    asm("v_cvt_pk_bf16_f32 %0, %1, %2" : "=v"(r) : "v"(lo), "v"(hi));
    return r;
}

// Two b32 writes in one DS instruction (offsets are 8-bit DWORD immediates).
template<int O0, int O1>
__device__ __forceinline__ void ds_write2(uint32_t* p, uint32_t a, uint32_t b) {
    asm volatile("ds_write2_b32 %0, %1, %2 offset0:%3 offset1:%4"
                 :: "v"((uint32_t)(uintptr_t)p), "v"(a), "v"(b), "i"(O0), "i"(O1)
                 : "memory");
}

// Overflow-safe softplus in log2 domain: g(u) = max(u,0) + log2(1 + 2^-|u|).
__device__ __forceinline__ float act_g(float u) {
    float e = __builtin_amdgcn_exp2f(-fabsf(u));
    return fmaxf(u, 0.0f) + __builtin_amdgcn_logf(1.0f + e);
}

// B-fragment, interleaved-pair permutation: elem j <-> k = kcb + lg*4 + (j>>1) + 16*(j&1)
__device__ __forceinline__ bf16x8 load_wfrag(const float* __restrict__ wg, int ldk,
                                             int f, int kcb, int lg, float scale) {
    const float4 a = *reinterpret_cast<const float4*>(wg + (size_t)f * ldk + kcb + lg * 4);
    const float4 b = *reinterpret_cast<const float4*>(wg + (size_t)f * ldk + kcb + 16 + lg * 4);
    short8 s;
    s[0] = (short)f2bf_bits(a.x * scale); s[1] = (short)f2bf_bits(b.x * scale);
    s[2] = (short)f2bf_bits(a.y * scale); s[3] = (short)f2bf_bits(b.y * scale);
    s[4] = (short)f2bf_bits(a.z * scale); s[5] = (short)f2bf_bits(b.z * scale);
    s[6] = (short)f2bf_bits(a.w * scale); s[7] = (short)f2bf_bits(b.w * scale);
    return __builtin_bit_cast(bf16x8, s);
}

// One hidden layer. src = &buf[lr][lg*4] (b128 reads at +kc*16 dwords, imm offsets);
// dst = &buf[lg*4][fbdw+lr]: rows j at +j*HS_LD, merged into 2x ds_write2_b32.
template<int NKC>
__device__ __forceinline__ void mlp_layer(const uint32_t* __restrict__ src,
                                          uint32_t* __restrict__ dst,
                                          const bf16x8* wf0, const bf16x8* wf1,
                                          float b0v, float b1v)
{
    f32x4 a0 = {b0v, b0v, b0v, b0v};
    f32x4 a1 = {b1v, b1v, b1v, b1v};
#pragma unroll
    for (int kc = 0; kc < NKC; ++kc) {
        const bf16x8 a = *reinterpret_cast<const bf16x8*>(src + kc * 16);
        a0 = __builtin_amdgcn_mfma_f32_16x16x32_bf16(a, wf0[kc], a0, 0, 0, 0);
        a1 = __builtin_amdgcn_mfma_f32_16x16x32_bf16(a, wf1[kc], a1, 0, 0, 0);
    }
    const uint32_t v0 = cvt_pk_bf16(act_g(a0[0]), act_g(a1[0]));
    const uint32_t v1 = cvt_pk_bf16(act_g(a0[1]), act_g(a1[1]));
    ds_write2<0, HS_LD>(dst, v0, v1);
    const uint32_t v2 = cvt_pk_bf16(act_g(a0[2]), act_g(a1[2]));
    const uint32_t v3 = cvt_pk_bf16(act_g(a0[3]), act_g(a1[3]));
    ds_write2<0, HS_LD>(dst + 2 * HS_LD, v2, v3);
}

__global__ __launch_bounds__(NTHREADS, 2) void node_rk3_kernel(
    const float* __restrict__ ts,
    const float* __restrict__ y0,
    const float* __restrict__ w0, const float* __restrict__ b0,
    const float* __restrict__ w1, const float* __restrict__ b1,
    const float* __restrict__ w2, const float* __restrict__ b2,
    const float* __restrict__ w3, const float* __restrict__ b3,
    float* __restrict__ out)
{
    __shared__ __align__(16) uint32_t hs0[ROWS_PB][HS_LD];
    __shared__ __align__(16) uint32_t hs1[ROWS_PB][HS_LD];
    __shared__ __align__(16) uint32_t ybf[ROWS_PB][YB_LD];

    const int tid  = threadIdx.x;
    const int lane = tid & 63;
    const int wid  = tid >> 6;
    const int lr   = lane & 15;
    const int lg   = lane >> 4;
    const int row0 = blockIdx.x * ROWS_PB;
    const int fbdw = wid * 16;           // dword base of this wave's 32-feat slice

    // ---- persistent register-resident weight fragments (pre-scaled) ----
    bf16x8 w0f[2][2], w1f[2][8], w2f[2][8], w3f[8];
#pragma unroll
    for (int nt = 0; nt < 2; ++nt) {
        const int f = wid * 32 + nt * 16 + lr;
#pragma unroll
        for (int kc = 0; kc < 2; ++kc) w0f[nt][kc] = load_wfrag(w0, D_DIM, f, kc * 32, lg, LOG2E);
#pragma unroll
        for (int kc = 0; kc < 8; ++kc) w1f[nt][kc] = load_wfrag(w1, W_DIM, f, kc * 32, lg, 1.0f);
#pragma unroll
        for (int kc = 0; kc < 8; ++kc) w2f[nt][kc] = load_wfrag(w2, W_DIM, f, kc * 32, lg, 1.0f);
    }
    const int f3 = (wid & 3) * 16;       // layer-3 feature base (waves 0..3 active)
#pragma unroll
    for (int kc = 0; kc < 8; ++kc) w3f[kc] = load_wfrag(w3, W_DIM, f3 + lr, kc * 32, lg, LN2);

    const float bA0 = LOG2E * b0[wid * 32 + lr], bB0 = LOG2E * b0[wid * 32 + 16 + lr];
    const float bA1 = LOG2E * b1[wid * 32 + lr], bB1 = LOG2E * b1[wid * 32 + 16 + lr];
    const float bA2 = LOG2E * b2[wid * 32 + lr], bB2 = LOG2E * b2[wid * 32 + 16 + lr];
    const float bv3 = b3[f3 + lr];

    const float dt = ts[1] - ts[0];

    // ---- per-thread LDS base pointers (all later accesses use imm offsets) ----
    const uint32_t* pA_y  = &ybf[lr][lg * 4];
    const uint32_t* pA_h0 = &hs0[lr][lg * 4];
    const uint32_t* pA_h1 = &hs1[lr][lg * 4];
    uint32_t* pW_h0 = &hs0[lg * 4][fbdw + lr];
    uint32_t* pW_h1 = &hs1[lg * 4][fbdw + lr];
    const int kb = wid >> 1, hi = wid & 1;          // ybf halfword write geometry (waves 0..3)
    uint16_t* pYW = (uint16_t*)&ybf[0][0] + ((size_t)(lg * 4) * YB_LD + kb * 16 + lr) * 2 + hi;

    // ---- per-lane state (waves 0..3): y[r=lg*4+j][d=f3+lr] ----
    float yreg[4], k1r[4], k2r[4], vst[4];
#pragma unroll
    for (int j = 0; j < 4; ++j) {
        yreg[j] = y0[(size_t)(row0 + lg * 4 + j) * D_DIM + f3 + lr];
        k1r[j] = 0.f; k2r[j] = 0.f; vst[j] = 0.f;
    }

    // ---- initial packed ybf ----
    for (int i = tid; i < ROWS_PB * 32; i += NTHREADS) {
        const int r = i >> 5, c32 = i & 31, kbi = c32 >> 4, u = c32 & 15;
        const float* yr = y0 + (size_t)(row0 + r) * D_DIM;
        ybf[r][kbi * 16 + u] = cvt_pk_bf16(yr[kbi * 32 + u], yr[kbi * 32 + 16 + u]);
    }
    __syncthreads();

    for (int t = 0; t < T_STEPS; ++t) {
        // deferred global store of step t-1 (overlaps with L0 compute of step t)
        if (wid < 4 && t > 0) {
#pragma unroll
            for (int j = 0; j < 4; ++j)
                out[((size_t)(t - 1) * B_ROWS + row0 + lg * 4 + j) * D_DIM + f3 + lr] = vst[j];
        }
#pragma unroll
        for (int c = 0; c < 3; ++c) {
            mlp_layer<2>(pA_y,  pW_h0, w0f[0], w0f[1], bA0, bB0);
            __syncthreads();
            mlp_layer<8>(pA_h0, pW_h1, w1f[0], w1f[1], bA1, bB1);
            __syncthreads();
            mlp_layer<8>(pA_h1, pW_h0, w2f[0], w2f[1], bA2, bB2);
            __syncthreads();
            // ---------- layer 3 + in-register RK update (waves 0..3) ----------
            if (wid < 4) {
                f32x4 acc = {bv3, bv3, bv3, bv3};
#pragma unroll
                for (int kc = 0; kc < 8; ++kc) {
                    const bf16x8 a = *reinterpret_cast<const bf16x8*>(pA_h0 + kc * 16);
                    acc = __builtin_amdgcn_mfma_f32_16x16x32_bf16(a, w3f[kc], acc, 0, 0, 0);
                }
#pragma unroll
                for (int j = 0; j < 4; ++j) {
                    float v;
                    if (c == 0)      { k1r[j] = acc[j]; v = fmaf(0.5f,  acc[j], yreg[j]); }
                    else if (c == 1) { k2r[j] = acc[j]; v = fmaf(0.75f, acc[j], yreg[j]); }
                    else {
                        v = yreg[j] + dt * ((2.0f / 9.0f) * k1r[j]
                                          + (1.0f / 3.0f) * k2r[j]
                                          + (4.0f / 9.0f) * acc[j]);
                        yreg[j] = v;
                        vst[j]  = v;
                    }
                    pYW[j * YB_LD * 2] = (uint16_t)cvt_pk_bf16(v, v);
                }
            }
            __syncthreads();
        }
    }
    // final step's store
    if (wid < 4) {
#pragma unroll
        for (int j = 0; j < 4; ++j)
            out[((size_t)(T_STEPS - 1) * B_ROWS + row0 + lg * 4 + j) * D_DIM + f3 + lr] = vst[j];
    }
}

extern "C" void kernel_launch(void* const* d_in, const int* in_sizes, int n_in,
                              void* d_out, int out_size, void* d_ws, size_t ws_size,
                              hipStream_t stream) {
    const float* ts = (const float*)d_in[0];
    const float* y0 = (const float*)d_in[1];
    const float* w0 = (const float*)d_in[2];
    const float* b0 = (const float*)d_in[3];
    const float* w1 = (const float*)d_in[4];
    const float* b1 = (const float*)d_in[5];
    const float* w2 = (const float*)d_in[6];
    const float* b2 = (const float*)d_in[7];
    const float* w3 = (const float*)d_in[8];
    const float* b3 = (const float*)d_in[9];
    float* out = (float*)d_out;

    hipLaunchKernelGGL(node_rk3_kernel,
                       dim3(B_ROWS / ROWS_PB), dim3(NTHREADS), 0, stream,
                       ts, y0, w0, b0, w1, b1, w2, b2, w3, b3, out);
}